// Round 2
// baseline (268.718 us; speedup 1.0000x reference)
//
#include <hip/hip_runtime.h>

#define BIG_F 1e10f
constexpr int B = 16;
constexpr int N = 4096;

// pack layout per set point j: { -2*s0, -2*s1, -2*s2, s·s + (valid ? 0 : BIG) }
// so dist(q, j) = qq + dot(q, pack.xyz) + pack.w, and qq hoists out of the min.

__global__ __launch_bounds__(256) void prep_kernel(
    const float* __restrict__ x, const float* __restrict__ y,
    const int* __restrict__ mask,
    float4* __restrict__ packx, float4* __restrict__ packy)
{
    int idx = blockIdx.x * 256 + threadIdx.x;   // 0 .. B*N-1
    int b = idx >> 12;                          // N == 4096
    int j = idx & (N - 1);
    float madd = mask[idx] ? 0.0f : BIG_F;

    const float* xb = x + (size_t)b * 3 * N;
    float x0 = xb[j], x1 = xb[N + j], x2 = xb[2 * N + j];
    float4 px;
    px.x = -2.0f * x0; px.y = -2.0f * x1; px.z = -2.0f * x2;
    px.w = fmaf(x2, x2, fmaf(x1, x1, x0 * x0)) + madd;
    packx[idx] = px;

    const float* yb = y + (size_t)b * 3 * N;
    float y0 = yb[j], y1 = yb[N + j], y2 = yb[2 * N + j];
    float4 py;
    py.x = -2.0f * y0; py.y = -2.0f * y1; py.z = -2.0f * y2;
    py.w = fmaf(y2, y2, fmaf(y1, y1, y0 * y0)) + madd;
    packy[idx] = py;
}

__global__ __launch_bounds__(256) void chamfer_main(
    const float* __restrict__ x, const float* __restrict__ y,
    const int* __restrict__ mask,
    const float4* __restrict__ packx, const float4* __restrict__ packy,
    float* __restrict__ sums)
{
    const int b   = blockIdx.y;
    const int dir = blockIdx.z;
    const int q   = blockIdx.x * 256 + threadIdx.x;  // query index within batch

    const float*  Q = (dir == 0 ? x : y) + (size_t)b * 3 * N;
    const float4* W = (dir == 0 ? packy : packx) + (size_t)b * N;

    const float q0 = Q[q], q1 = Q[N + q], q2 = Q[2 * N + q];
    const float qq = fmaf(q2, q2, fmaf(q1, q1, q0 * q0));

    float m0 = BIG_F, m1 = BIG_F, m2 = BIG_F, m3 = BIG_F;
    for (int j = 0; j < N; j += 4) {
        float4 w0 = W[j + 0];
        float4 w1 = W[j + 1];
        float4 w2 = W[j + 2];
        float4 w3 = W[j + 3];
        m0 = fminf(m0, fmaf(q0, w0.x, fmaf(q1, w0.y, fmaf(q2, w0.z, w0.w))));
        m1 = fminf(m1, fmaf(q0, w1.x, fmaf(q1, w1.y, fmaf(q2, w1.z, w1.w))));
        m2 = fminf(m2, fmaf(q0, w2.x, fmaf(q1, w2.y, fmaf(q2, w2.z, w2.w))));
        m3 = fminf(m3, fmaf(q0, w3.x, fmaf(q1, w3.y, fmaf(q2, w3.z, w3.w))));
    }
    float minv = fminf(fminf(m0, m1), fminf(m2, m3));

    // masked contribution of this query point
    float val = (mask[b * N + q] != 0) ? (qq + minv) : 0.0f;

    // wave (64-lane) shuffle reduction, then cross-wave via LDS
    for (int off = 32; off > 0; off >>= 1) val += __shfl_down(val, off);
    __shared__ float red[4];
    const int wave = threadIdx.x >> 6;
    if ((threadIdx.x & 63) == 0) red[wave] = val;
    __syncthreads();
    if (threadIdx.x == 0) {
        atomicAdd(&sums[b], red[0] + red[1] + red[2] + red[3]);
    }
}

__global__ __launch_bounds__(256) void finalize_kernel(
    const int* __restrict__ mask, const float* __restrict__ sums,
    float* __restrict__ out)
{
    __shared__ float red[4];
    float total = 0.0f;  // only thread 0's copy matters
    for (int b = 0; b < B; ++b) {
        int c = 0;
        for (int j = threadIdx.x; j < N; j += 256) c += mask[b * N + j];
        float val = (float)c;
        for (int off = 32; off > 0; off >>= 1) val += __shfl_down(val, off);
        if ((threadIdx.x & 63) == 0) red[threadIdx.x >> 6] = val;
        __syncthreads();
        if (threadIdx.x == 0) {
            float cnt = red[0] + red[1] + red[2] + red[3];
            total += sums[b] / cnt;
        }
        __syncthreads();
    }
    if (threadIdx.x == 0) out[0] = total / (float)B;
}

extern "C" void kernel_launch(void* const* d_in, const int* in_sizes, int n_in,
                              void* d_out, int out_size, void* d_ws, size_t ws_size,
                              hipStream_t stream) {
    const float* x    = (const float*)d_in[0];
    const float* y    = (const float*)d_in[1];
    const int*   mask = (const int*)d_in[2];

    float4* packx = (float4*)d_ws;
    float4* packy = packx + (size_t)B * N;
    float*  sums  = (float*)(packy + (size_t)B * N);

    hipMemsetAsync(sums, 0, B * sizeof(float), stream);
    prep_kernel<<<dim3(B * N / 256), 256, 0, stream>>>(x, y, mask, packx, packy);
    chamfer_main<<<dim3(N / 256, B, 2), 256, 0, stream>>>(x, y, mask, packx, packy, sums);
    finalize_kernel<<<1, 256, 0, stream>>>(mask, sums, (float*)d_out);
}

// Round 4
// 137.754 us; speedup vs baseline: 1.9507x; 1.9507x over previous
//
#include <hip/hip_runtime.h>

#define BIG_F 1e10f
constexpr int B = 16;
constexpr int N = 4096;
constexpr int QPT = 4;      // queries per thread
constexpr int SCHUNK = 512; // set points per block (N/SCHUNK = 8 chunks)

// pack layout per set point j: { -2*s0, -2*s1, -2*s2, s·s + (valid ? 0 : BIG) }
// dist(q, j) = qq + dot(q, pack.xyz) + pack.w; qq hoists out of the min.

__global__ __launch_bounds__(256) void prep_kernel(
    const float* __restrict__ x, const float* __restrict__ y,
    const int* __restrict__ mask,
    float4* __restrict__ packx, float4* __restrict__ packy)
{
    int idx = blockIdx.x * 256 + threadIdx.x;   // 0 .. B*N-1
    int b = idx >> 12;                          // N == 4096
    int j = idx & (N - 1);
    float madd = mask[idx] ? 0.0f : BIG_F;

    const float* xb = x + (size_t)b * 3 * N;
    float x0 = xb[j], x1 = xb[N + j], x2 = xb[2 * N + j];
    float4 px;
    px.x = -2.0f * x0; px.y = -2.0f * x1; px.z = -2.0f * x2;
    px.w = fmaf(x2, x2, fmaf(x1, x1, x0 * x0)) + madd;
    packx[idx] = px;

    const float* yb = y + (size_t)b * 3 * N;
    float y0 = yb[j], y1 = yb[N + j], y2 = yb[2 * N + j];
    float4 py;
    py.x = -2.0f * y0; py.y = -2.0f * y1; py.z = -2.0f * y2;
    py.w = fmaf(y2, y2, fmaf(y1, y1, y0 * y0)) + madd;
    packy[idx] = py;
}

// monotonic float->uint key: preserves order for ALL floats (incl. tiny negatives)
__device__ __forceinline__ unsigned enc_key(float f) {
    unsigned bits = __float_as_uint(f);
    return (bits & 0x80000000u) ? ~bits : (bits | 0x80000000u);
}
__device__ __forceinline__ float dec_key(unsigned key) {
    unsigned bits = (key & 0x80000000u) ? (key ^ 0x80000000u) : ~key;
    return __uint_as_float(bits);
}

__global__ __launch_bounds__(256) void chamfer_main(
    const float* __restrict__ x, const float* __restrict__ y,
    const float4* __restrict__ packx, const float4* __restrict__ packy,
    unsigned* __restrict__ minarr)
{
    const int qt  = blockIdx.x & 3;   // query tile 0..3 (1024 queries each)
    const int sc  = blockIdx.x >> 2;  // set chunk 0..7 (512 set points each)
    const int b   = blockIdx.y;
    const int dir = blockIdx.z;

    const float*  Q = (dir == 0 ? x : y) + (size_t)b * 3 * N;
    const float4* W = (dir == 0 ? packy : packx) + (size_t)b * N + sc * SCHUNK;
    unsigned* Mrow = minarr + (((dir * B) + b) << 12) + qt * 1024 + threadIdx.x;

    float qx[QPT], qy[QPT], qz[QPT], m[QPT];
    const int qbase = qt * 1024 + threadIdx.x;
#pragma unroll
    for (int k = 0; k < QPT; ++k) {
        int q = qbase + k * 256;
        qx[k] = Q[q]; qy[k] = Q[N + q]; qz[k] = Q[2 * N + q];
        m[k] = 1e30f;
    }

    auto do_point = [&](const float4 wp) {
#pragma unroll
        for (int k = 0; k < QPT; ++k)
            m[k] = fminf(m[k],
                fmaf(qx[k], wp.x, fmaf(qy[k], wp.y, fmaf(qz[k], wp.z, wp.w))));
    };

    // manual software pipeline: prefetch next 4 set points (wave-uniform
    // scalar loads) while computing on the current 4
    float4 w0 = W[0], w1 = W[1], w2 = W[2], w3 = W[3];
    for (int p = 0; p < SCHUNK - 4; p += 4) {
        float4 n0 = W[p + 4], n1 = W[p + 5], n2 = W[p + 6], n3 = W[p + 7];
        do_point(w0); do_point(w1); do_point(w2); do_point(w3);
        w0 = n0; w1 = n1; w2 = n2; w3 = n3;
    }
    do_point(w0); do_point(w1); do_point(w2); do_point(w3);

#pragma unroll
    for (int k = 0; k < QPT; ++k) {
        float qq = fmaf(qz[k], qz[k], fmaf(qy[k], qy[k], qx[k] * qx[k]));
        atomicMin(Mrow + k * 256, enc_key(qq + m[k]));
    }
}

__global__ __launch_bounds__(256) void finalize_kernel(
    const int* __restrict__ mask, const unsigned* __restrict__ minarr,
    float* __restrict__ out)
{
    const int b = blockIdx.x >> 1, dir = blockIdx.x & 1;
    const unsigned* Mrow = minarr + (((dir * B) + b) << 12);
    const int* mrow = mask + b * N;

    float s = 0.0f, c = 0.0f;
    for (int q = threadIdx.x; q < N; q += 256) {
        int mk = mrow[q];
        float v = dec_key(Mrow[q]);
        if (mk) { s += v; c += 1.0f; }
    }
    for (int off = 32; off > 0; off >>= 1) {
        s += __shfl_down(s, off);
        c += __shfl_down(c, off);
    }
    __shared__ float rs[4], rc[4];
    const int wv = threadIdx.x >> 6;
    if ((threadIdx.x & 63) == 0) { rs[wv] = s; rc[wv] = c; }
    __syncthreads();
    if (threadIdx.x == 0) {
        float S = rs[0] + rs[1] + rs[2] + rs[3];
        float C = rc[0] + rc[1] + rc[2] + rc[3];
        atomicAdd(out, (S / C) * (1.0f / (float)B));
    }
}

extern "C" void kernel_launch(void* const* d_in, const int* in_sizes, int n_in,
                              void* d_out, int out_size, void* d_ws, size_t ws_size,
                              hipStream_t stream) {
    const float* x    = (const float*)d_in[0];
    const float* y    = (const float*)d_in[1];
    const int*   mask = (const int*)d_in[2];

    float4*   packx  = (float4*)d_ws;
    float4*   packy  = packx + (size_t)B * N;
    unsigned* minarr = (unsigned*)(packy + (size_t)B * N);  // 2*B*N uints = 512KB

    (void)hipMemsetAsync(d_out, 0, sizeof(float), stream);
    (void)hipMemsetAsync(minarr, 0xFF, (size_t)2 * B * N * sizeof(unsigned), stream);
    prep_kernel<<<dim3(B * N / 256), 256, 0, stream>>>(x, y, mask, packx, packy);
    chamfer_main<<<dim3((N / 1024) * (N / SCHUNK), B, 2), 256, 0, stream>>>(
        x, y, packx, packy, minarr);
    finalize_kernel<<<dim3(2 * B), 256, 0, stream>>>(mask, minarr, (float*)d_out);
}

// Round 5
// 120.347 us; speedup vs baseline: 2.2329x; 1.1446x over previous
//
#include <hip/hip_runtime.h>

#define BIG_F 1e10f
constexpr int B = 16;
constexpr int N = 4096;
constexpr int QPT = 8;      // queries per thread (2048 queries per block)
constexpr int SCHUNK = 256; // set points per block (N/SCHUNK = 16 chunks)

// pack layout per set point j: { -2*s0, -2*s1, -2*s2, s·s + (valid ? 0 : BIG) }
// dist(q, j) = qq + dot(q, pack.xyz) + pack.w; qq hoists out of the min.

__global__ __launch_bounds__(256) void prep_kernel(
    const float* __restrict__ x, const float* __restrict__ y,
    const int* __restrict__ mask,
    float4* __restrict__ packx, float4* __restrict__ packy,
    unsigned* __restrict__ minarr, float* __restrict__ out)
{
    int idx = blockIdx.x * 256 + threadIdx.x;   // 0 .. B*N-1
    int b = idx >> 12;                          // N == 4096
    int j = idx & (N - 1);
    float madd = mask[idx] ? 0.0f : BIG_F;

    const float* xb = x + (size_t)b * 3 * N;
    float x0 = xb[j], x1 = xb[N + j], x2 = xb[2 * N + j];
    float4 px;
    px.x = -2.0f * x0; px.y = -2.0f * x1; px.z = -2.0f * x2;
    px.w = fmaf(x2, x2, fmaf(x1, x1, x0 * x0)) + madd;
    packx[idx] = px;

    const float* yb = y + (size_t)b * 3 * N;
    float y0 = yb[j], y1 = yb[N + j], y2 = yb[2 * N + j];
    float4 py;
    py.x = -2.0f * y0; py.y = -2.0f * y1; py.z = -2.0f * y2;
    py.w = fmaf(y2, y2, fmaf(y1, y1, y0 * y0)) + madd;
    packy[idx] = py;

    // fused init (replaces two hipMemsetAsync dispatches)
    minarr[idx] = 0xFFFFFFFFu;
    minarr[idx + B * N] = 0xFFFFFFFFu;
    if (idx == 0) out[0] = 0.0f;
}

// monotonic float->uint key: preserves order for ALL floats (incl. tiny negatives)
__device__ __forceinline__ unsigned enc_key(float f) {
    unsigned bits = __float_as_uint(f);
    return (bits & 0x80000000u) ? ~bits : (bits | 0x80000000u);
}
__device__ __forceinline__ float dec_key(unsigned key) {
    unsigned bits = (key & 0x80000000u) ? (key ^ 0x80000000u) : ~key;
    return __uint_as_float(bits);
}

__global__ __launch_bounds__(256) void chamfer_main(
    const float* __restrict__ x, const float* __restrict__ y,
    const float4* __restrict__ packx, const float4* __restrict__ packy,
    unsigned* __restrict__ minarr)
{
    const int qt  = blockIdx.x & 1;   // query tile 0..1 (2048 queries each)
    const int sc  = blockIdx.x >> 1;  // set chunk 0..15 (256 set points each)
    const int b   = blockIdx.y;
    const int dir = blockIdx.z;

    const float*  Q = (dir == 0 ? x : y) + (size_t)b * 3 * N;
    const float4* W = (dir == 0 ? packy : packx) + (size_t)b * N + sc * SCHUNK;
    unsigned* Mrow = minarr + (((dir * B) + b) << 12) + qt * 2048 + threadIdx.x;

    float qx[QPT], qy[QPT], qz[QPT], m[QPT];
    const int qbase = qt * 2048 + threadIdx.x;
#pragma unroll
    for (int k = 0; k < QPT; ++k) {
        int q = qbase + k * 256;
        qx[k] = Q[q]; qy[k] = Q[N + q]; qz[k] = Q[2 * N + q];
        m[k] = 1e30f;
    }

    auto do_point = [&](const float4 wp) {
#pragma unroll
        for (int k = 0; k < QPT; ++k)
            m[k] = fminf(m[k],
                fmaf(qx[k], wp.x, fmaf(qy[k], wp.y, fmaf(qz[k], wp.z, wp.w))));
    };

    // software pipeline: prefetch next 4 set points (wave-uniform scalar
    // loads) while computing on the current 4 (128 VALU ops per 64B loaded)
    float4 w0 = W[0], w1 = W[1], w2 = W[2], w3 = W[3];
    for (int p = 0; p < SCHUNK - 4; p += 4) {
        float4 n0 = W[p + 4], n1 = W[p + 5], n2 = W[p + 6], n3 = W[p + 7];
        do_point(w0); do_point(w1); do_point(w2); do_point(w3);
        w0 = n0; w1 = n1; w2 = n2; w3 = n3;
    }
    do_point(w0); do_point(w1); do_point(w2); do_point(w3);

#pragma unroll
    for (int k = 0; k < QPT; ++k) {
        float qq = fmaf(qz[k], qz[k], fmaf(qy[k], qy[k], qx[k] * qx[k]));
        atomicMin(Mrow + k * 256, enc_key(qq + m[k]));
    }
}

__global__ __launch_bounds__(256) void finalize_kernel(
    const int* __restrict__ mask, const unsigned* __restrict__ minarr,
    float* __restrict__ out)
{
    const int b = blockIdx.x >> 1, dir = blockIdx.x & 1;
    const unsigned* Mrow = minarr + (((dir * B) + b) << 12);
    const int* mrow = mask + b * N;

    float s = 0.0f, c = 0.0f;
    for (int q = threadIdx.x; q < N; q += 256) {
        int mk = mrow[q];
        float v = dec_key(Mrow[q]);
        if (mk) { s += v; c += 1.0f; }
    }
    for (int off = 32; off > 0; off >>= 1) {
        s += __shfl_down(s, off);
        c += __shfl_down(c, off);
    }
    __shared__ float rs[4], rc[4];
    const int wv = threadIdx.x >> 6;
    if ((threadIdx.x & 63) == 0) { rs[wv] = s; rc[wv] = c; }
    __syncthreads();
    if (threadIdx.x == 0) {
        float S = rs[0] + rs[1] + rs[2] + rs[3];
        float C = rc[0] + rc[1] + rc[2] + rc[3];
        atomicAdd(out, (S / C) * (1.0f / (float)B));
    }
}

extern "C" void kernel_launch(void* const* d_in, const int* in_sizes, int n_in,
                              void* d_out, int out_size, void* d_ws, size_t ws_size,
                              hipStream_t stream) {
    const float* x    = (const float*)d_in[0];
    const float* y    = (const float*)d_in[1];
    const int*   mask = (const int*)d_in[2];

    float4*   packx  = (float4*)d_ws;
    float4*   packy  = packx + (size_t)B * N;
    unsigned* minarr = (unsigned*)(packy + (size_t)B * N);  // 2*B*N uints = 512KB

    prep_kernel<<<dim3(B * N / 256), 256, 0, stream>>>(
        x, y, mask, packx, packy, minarr, (float*)d_out);
    chamfer_main<<<dim3((N / 2048) * (N / SCHUNK), B, 2), 256, 0, stream>>>(
        x, y, packx, packy, minarr);
    finalize_kernel<<<dim3(2 * B), 256, 0, stream>>>(mask, minarr, (float*)d_out);
}